// Round 1
// 565.135 us; speedup vs baseline: 1.0677x; 1.0677x over previous
//
#include <hip/hip_runtime.h>
#include <cstdint>
#include <cstddef>

#define BN_EPS 1e-5f
#define BKT 256        // buckets (dst>>9), 512 nodes each; 100000>>9 = 195 -> 196 used
#define BSH 9
#define CHUNK 8192     // edges per block in hist/scatter

// ---- manual bf16 helpers (hip_bf16.h intrinsics unavailable in this ROCm) ----
__device__ __forceinline__ unsigned int f32_to_bf16_rne(float f) {
    unsigned int u = __float_as_uint(f);
    u += 0x7FFFu + ((u >> 16) & 1u);
    return u >> 16;
}
__device__ __forceinline__ unsigned int pack_bf16x2(float a, float b) {
    return f32_to_bf16_rne(a) | (f32_to_bf16_rne(b) << 16);
}
__device__ __forceinline__ float bf16_lo(unsigned int p) { return __uint_as_float(p << 16); }
__device__ __forceinline__ float bf16_hi(unsigned int p) { return __uint_as_float(p & 0xFFFF0000u); }

// ---------------- bucketed CSR build ----------------
// Phase 1: per-(bucket,block) histogram H[b*G+g]
__global__ void hist_kernel(const int* __restrict__ dst, int* __restrict__ H, int e, int G) {
    __shared__ int h[BKT];
    int t = threadIdx.x, g = blockIdx.x;
    h[t] = 0;
    __syncthreads();
    int base = g * CHUNK;
#pragma unroll
    for (int i = 0; i < CHUNK / 256; i++) {
        int idx = base + i * 256 + t;
        if (idx < e) atomicAdd(&h[dst[idx] >> BSH], 1);
    }
    __syncthreads();
    H[t * G + g] = h[t];
}

// Phase 3: scatter (src,dst) into bucket-contiguous binned array.
__global__ void bin_scatter_kernel(const int* __restrict__ src, const int* __restrict__ dst,
                                   const int* __restrict__ Hscan, uint2* __restrict__ binned,
                                   int e, int G) {
    __shared__ int cur[BKT];
    int t = threadIdx.x, g = blockIdx.x;
    cur[t] = Hscan[t * G + g];
    __syncthreads();
    int base = g * CHUNK;
#pragma unroll
    for (int i = 0; i < CHUNK / 256; i++) {
        int idx = base + i * 256 + t;
        if (idx < e) {
            int s = src[idx], d = dst[idx];
            int pos = atomicAdd(&cur[d >> BSH], 1);
            uint2 v; v.x = (unsigned)s; v.y = (unsigned)d;
            binned[pos] = v;
        }
    }
}

// Phase 4: one block per bucket (512 nodes). Count degrees, local scan,
// write cnt/rowptr/dinv, then fill esrc -- all cursors/counts in LDS.
__global__ __launch_bounds__(256) void bucket_build_kernel(const uint2* __restrict__ binned,
                                                           const int* __restrict__ Hscan,
                                                           int* __restrict__ cnt,
                                                           int* __restrict__ rowptr,
                                                           float* __restrict__ dinv,
                                                           int* __restrict__ esrc,
                                                           int e, int G, int n) {
    __shared__ int lcnt[512], lexc[512], ssum[256];
    const int t = threadIdx.x;
    const int b = blockIdx.x;
    const int start = Hscan[b * G];
    const int end = (b == BKT - 1) ? e : Hscan[(b + 1) * G];

    lcnt[t] = 0; lcnt[t + 256] = 0;
    __syncthreads();
    for (int i = start + t; i < end; i += 256)
        atomicAdd(&lcnt[binned[i].y & 511], 1);
    __syncthreads();

    int a0 = lcnt[2 * t], a1 = lcnt[2 * t + 1];
    ssum[t] = a0 + a1;
    __syncthreads();
    for (int off = 1; off < 256; off <<= 1) {
        int v = (t >= off) ? ssum[t - off] : 0;
        __syncthreads();
        ssum[t] += v;
        __syncthreads();
    }
    int excl = (t == 0) ? 0 : ssum[t - 1];
    lexc[2 * t] = excl;
    lexc[2 * t + 1] = excl + a0;
    __syncthreads();

    int nodebase = b << BSH;
#pragma unroll
    for (int j2 = 0; j2 < 2; j2++) {
        int j = 2 * t + j2;
        int node = nodebase + j;
        if (node < n) {
            int c = lcnt[j];
            cnt[node] = c;
            rowptr[node] = start + lexc[j];
            dinv[node] = rsqrtf((float)(c + 1));
        }
    }
    __syncthreads();

    for (int i = start + t; i < end; i += 256) {
        uint2 ed = binned[i];
        int pos = start + atomicAdd(&lexc[ed.y & 511], 1);
        esrc[pos] = (int)ed.x;
    }
}

// ---- scan helpers for H (bucket-major (bucket,block) histogram) ----

__global__ void blocksum_kernel(const int* __restrict__ in, int* __restrict__ bsum, int n) {
    int t = threadIdx.x;
    int base = blockIdx.x * 1024 + t * 4;
    int s = 0;
    if (base + 3 < n) {
        int4 v = *(const int4*)&in[base];
        s = v.x + v.y + v.z + v.w;
    } else {
        for (int j = 0; j < 4; j++) if (base + j < n) s += in[base + j];
    }
    __shared__ int ls[256];
    ls[t] = s;
    __syncthreads();
    for (int off = 128; off > 0; off >>= 1) {
        if (t < off) ls[t] += ls[t + off];
        __syncthreads();
    }
    if (t == 0) bsum[blockIdx.x] = ls[0];
}

__global__ void scan_bsum_kernel(int* __restrict__ bsum, int nb) {
    int t = threadIdx.x;
    __shared__ int ls[256];
    int v = (t < nb) ? bsum[t] : 0;
    ls[t] = v;
    __syncthreads();
    for (int off = 1; off < 256; off <<= 1) {
        int p = (t >= off) ? ls[t - off] : 0;
        __syncthreads();
        ls[t] += p;
        __syncthreads();
    }
    if (t < nb) bsum[t] = ls[t] - v;   // inclusive -> exclusive
}

__global__ void scan_write1_kernel(const int* __restrict__ in, const int* __restrict__ bsum,
                                   int* __restrict__ out, int n) {
    int t = threadIdx.x;
    int base = blockIdx.x * 1024 + t * 4;
    int v[4];
    int s = 0;
    if (base + 3 < n) {
        int4 q = *(const int4*)&in[base];
        v[0] = q.x; v[1] = q.y; v[2] = q.z; v[3] = q.w;
        s = q.x + q.y + q.z + q.w;
    } else {
        for (int j = 0; j < 4; j++) { v[j] = (base + j < n) ? in[base + j] : 0; s += v[j]; }
    }
    __shared__ int ls[256];
    ls[t] = s;
    __syncthreads();
    for (int off = 1; off < 256; off <<= 1) {
        int p = (t >= off) ? ls[t - off] : 0;
        __syncthreads();
        ls[t] += p;
        __syncthreads();
    }
    int run = bsum[blockIdx.x] + ls[t] - s;
    if (base + 3 < n) {
        int4 r; r.x = run; r.y = run + v[0]; r.z = run + v[0] + v[1]; r.w = run + v[0] + v[1] + v[2];
        *(int4*)&out[base] = r;
    } else {
        for (int j = 0; j < 4; j++) {
            if (base + j < n) out[base + j] = run;
            run += v[j];
        }
    }
}

// ---------------- GEMM: Y[n,OUTC](bf16) = dinv[r] * act(X[n,128]) @ W[128,OUTC] ----------------
// NOTE: output rows are PRE-SCALED by dinv[row] so the aggregation kernels need
// no per-edge dinv gather: out[d] = dinv[d]*(sum_{s in N(d)} xw'[s] + xw'[d]) + b.

template <int OUTC>
__global__ __launch_bounds__(256) void gemm_kernel(const float* __restrict__ X,
                                                   const float* __restrict__ W,
                                                   const float* __restrict__ scale,
                                                   const float* __restrict__ shift,
                                                   const float* __restrict__ dinv,
                                                   unsigned int* __restrict__ Y, int n) {
    constexpr int RPT = (OUTC == 128) ? 8 : 4;  // rows per thread
    constexpr int CG  = OUTC / 4;               // col groups (4 cols each)
    __shared__ float lXT[128 * 68];             // [k][row], 34.8 KB
    __shared__ float ldv[64];
    const int t = threadIdx.x;
    const int base = blockIdx.x * 64;
    const bool bn = (scale != nullptr);

    if (t < 64) {
        int r = base + t;
        ldv[t] = (r < n) ? dinv[r] : 0.0f;
    }

#pragma unroll
    for (int i = 0; i < 8; i++) {
        int id = i * 256 + t;
        int k  = id & 127;
        int r4 = id >> 7;  // 0..15
        float sc = 1.0f, sh = 0.0f;
        if (bn) { sc = scale[k]; sh = shift[k]; }
        float v[4];
#pragma unroll
        for (int j = 0; j < 4; j++) {
            int r = base + r4 * 4 + j;
            float xv = 0.0f;
            if (r < n) xv = X[(size_t)r * 128 + k];
            if (bn) xv = fmaxf(fmaf(xv, sc, sh), 0.0f);
            v[j] = xv;
        }
        float4 vv; vv.x = v[0]; vv.y = v[1]; vv.z = v[2]; vv.w = v[3];
        *(float4*)&lXT[k * 68 + r4 * 4] = vv;
    }
    __syncthreads();

    const int cg = t % CG;
    const int rg = t / CG;
    float acc[RPT][4];
#pragma unroll
    for (int i = 0; i < RPT; i++)
#pragma unroll
        for (int j = 0; j < 4; j++) acc[i][j] = 0.0f;

#pragma unroll 4
    for (int k = 0; k < 128; k++) {
        float4 b = *(const float4*)&W[k * OUTC + cg * 4];
        float a[RPT];
        *(float4*)&a[0] = *(const float4*)&lXT[k * 68 + rg * RPT];
        if constexpr (RPT == 8)
            *(float4*)&a[4] = *(const float4*)&lXT[k * 68 + rg * RPT + 4];
#pragma unroll
        for (int i = 0; i < RPT; i++) {
            acc[i][0] = fmaf(a[i], b.x, acc[i][0]);
            acc[i][1] = fmaf(a[i], b.y, acc[i][1]);
            acc[i][2] = fmaf(a[i], b.z, acc[i][2]);
            acc[i][3] = fmaf(a[i], b.w, acc[i][3]);
        }
    }

#pragma unroll
    for (int i = 0; i < RPT; i++) {
        int r = base + rg * RPT + i;
        if (r < n) {
            float dv = ldv[rg * RPT + i];
            uint2 o;
            o.x = pack_bf16x2(acc[i][0] * dv, acc[i][1] * dv);
            o.y = pack_bf16x2(acc[i][2] * dv, acc[i][3] * dv);
            *(uint2*)&Y[(size_t)r * (OUTC / 2) + cg * 2] = o;
        }
    }
}

// ---------------- aggregation (128 cols): one wave per node ----------------
// xw rows are pre-scaled by dinv[src]. out[d] = dinv[d]*(sum xw'[s] + xw'[d]) + b.
// Fully predicated 8-edge batches (clamped index -> no serial tail, no extra
// cache lines), esrc batch software-pipelined one batch ahead, node-uniform
// values readfirstlane'd so edge-list loads take the scalar path.

__global__ __launch_bounds__(256) void agg128_kernel(const unsigned int* __restrict__ xw,
                                                     const int* __restrict__ rowptr,
                                                     const int* __restrict__ cnt,
                                                     const int* __restrict__ esrc,
                                                     const float* __restrict__ dinv,
                                                     const float* __restrict__ bias,
                                                     float* __restrict__ out, int n) {
    int gid = blockIdx.x * 256 + threadIdx.x;
    int node = __builtin_amdgcn_readfirstlane(gid >> 6);
    if (node >= n) return;
    int lane = threadIdx.x & 63;
    float di = dinv[node];
    int beg = __builtin_amdgcn_readfirstlane(rowptr[node]);
    int cv  = __builtin_amdgcn_readfirstlane(cnt[node]);
    int last = beg + cv - 1;

    unsigned int ap = xw[(size_t)node * 64 + lane];
    float ax = bf16_lo(ap), ay = bf16_hi(ap);

    int nb = (cv + 7) >> 3;
    int s[8], sn[8];
    if (nb > 0) {
#pragma unroll
        for (int j = 0; j < 8; j++) {
            int idx = beg + j;
            s[j] = esrc[idx <= last ? idx : last];
        }
    }
    for (int b = 0; b < nb; b++) {
        int ebase = beg + b * 8;
        if (b + 1 < nb) {
#pragma unroll
            for (int j = 0; j < 8; j++) {
                int idx = ebase + 8 + j;
                sn[j] = esrc[idx <= last ? idx : last];
            }
        }
        unsigned int v[8];
#pragma unroll
        for (int j = 0; j < 8; j++) v[j] = xw[(size_t)s[j] * 64 + lane];
        int rem = last - ebase;   // valid lanes: j <= rem (wave-uniform)
#pragma unroll
        for (int j = 0; j < 8; j++) {
            float m = (j <= rem) ? 1.0f : 0.0f;
            ax = fmaf(m, bf16_lo(v[j]), ax);
            ay = fmaf(m, bf16_hi(v[j]), ay);
        }
        if (b + 1 < nb) {
#pragma unroll
            for (int j = 0; j < 8; j++) s[j] = sn[j];
        }
    }
    float2 bv = ((const float2*)bias)[lane];
    float2 o; o.x = fmaf(di, ax, bv.x); o.y = fmaf(di, ay, bv.y);
    ((float2*)(out + (size_t)node * 128))[lane] = o;
}

// ---------------- aggregation (64-col output layer) ----------------

__global__ __launch_bounds__(256) void agg64_kernel(const unsigned int* __restrict__ xw,
                                                    const int* __restrict__ rowptr,
                                                    const int* __restrict__ cnt,
                                                    const int* __restrict__ esrc,
                                                    const float* __restrict__ dinv,
                                                    const float* __restrict__ bias,
                                                    float* __restrict__ out, int n) {
    int gid = blockIdx.x * 256 + threadIdx.x;
    int node = __builtin_amdgcn_readfirstlane(gid >> 6);
    if (node >= n) return;
    int lane = threadIdx.x & 63;
    int col = lane >> 1;
    bool hi = (lane & 1) != 0;
    float di = dinv[node];
    int beg = __builtin_amdgcn_readfirstlane(rowptr[node]);
    int cv  = __builtin_amdgcn_readfirstlane(cnt[node]);
    int last = beg + cv - 1;

    unsigned int ap = xw[(size_t)node * 32 + col];
    float acc = hi ? bf16_hi(ap) : bf16_lo(ap);

    int nb = (cv + 7) >> 3;
    int s[8], sn[8];
    if (nb > 0) {
#pragma unroll
        for (int j = 0; j < 8; j++) {
            int idx = beg + j;
            s[j] = esrc[idx <= last ? idx : last];
        }
    }
    for (int b = 0; b < nb; b++) {
        int ebase = beg + b * 8;
        if (b + 1 < nb) {
#pragma unroll
            for (int j = 0; j < 8; j++) {
                int idx = ebase + 8 + j;
                sn[j] = esrc[idx <= last ? idx : last];
            }
        }
        unsigned int v[8];
#pragma unroll
        for (int j = 0; j < 8; j++) v[j] = xw[(size_t)s[j] * 32 + col];
        int rem = last - ebase;
#pragma unroll
        for (int j = 0; j < 8; j++) {
            float m = (j <= rem) ? 1.0f : 0.0f;
            float vf = hi ? bf16_hi(v[j]) : bf16_lo(v[j]);
            acc = fmaf(m, vf, acc);
        }
        if (b + 1 < nb) {
#pragma unroll
            for (int j = 0; j < 8; j++) s[j] = sn[j];
        }
    }
    out[(size_t)node * 64 + lane] = fmaf(di, acc, bias[lane]);
}

// ---------------- BatchNorm (training-mode, biased var) ----------------

__global__ void bn_stats_kernel(const float* __restrict__ h, float* __restrict__ sums, int n) {
    int c = threadIdx.x & 127;
    int half = threadIdx.x >> 7;
    float s = 0.0f, q = 0.0f;
    for (int r = blockIdx.x * 2 + half; r < n; r += gridDim.x * 2) {
        float v = h[(size_t)r * 128 + c];
        s += v;
        q = fmaf(v, v, q);
    }
    __shared__ float ls[256], lq[256];
    ls[threadIdx.x] = s; lq[threadIdx.x] = q;
    __syncthreads();
    if (half == 0) {
        s += ls[c + 128];
        q += lq[c + 128];
        atomicAdd(&sums[c], s);
        atomicAdd(&sums[128 + c], q);
    }
}

__global__ void bn_finalize_kernel(const float* __restrict__ sums, const float* __restrict__ g,
                                   const float* __restrict__ be, float* __restrict__ scale,
                                   float* __restrict__ shift, int n) {
    int c = threadIdx.x;  // 128 threads
    float inv_n = 1.0f / (float)n;
    float mean = sums[c] * inv_n;
    float var = sums[128 + c] * inv_n - mean * mean;
    float rstd = rsqrtf(var + BN_EPS);
    float sc = rstd * g[c];
    scale[c] = sc;
    shift[c] = be[c] - mean * sc;
}

// ---------------- launch ----------------

extern "C" void kernel_launch(void* const* d_in, const int* in_sizes, int n_in,
                              void* d_out, int out_size, void* d_ws, size_t ws_size,
                              hipStream_t stream) {
    const float* x   = (const float*)d_in[0];
    const int*   ei  = (const int*)d_in[1];
    const float* W1  = (const float*)d_in[2];
    const float* b1  = (const float*)d_in[3];
    const float* g1  = (const float*)d_in[4];
    const float* be1 = (const float*)d_in[5];
    const float* W2  = (const float*)d_in[6];
    const float* b2  = (const float*)d_in[7];
    const float* g2  = (const float*)d_in[8];
    const float* be2 = (const float*)d_in[9];
    const float* W3  = (const float*)d_in[10];
    const float* b3  = (const float*)d_in[11];

    const int n = in_sizes[0] / 128;
    const int E = in_sizes[1] / 2;
    const int* srcv = ei;
    const int* dstv = ei + E;

    const int G = (E + CHUNK - 1) / CHUNK;      // hist/scatter blocks (196)
    const int HN = BKT * G;                      // H matrix elements (50176)
    const int NB = (n + 511) >> 9;               // used buckets (196)

    char* p = (char*)d_ws;
    auto carve = [&](size_t bytes) -> char* {
        char* q = p;
        p += (bytes + 255) & ~(size_t)255;
        return q;
    };
    int*   cnt    = (int*)carve((size_t)n * 4);
    int*   rowptr = (int*)carve((size_t)n * 4);
    float* dinv   = (float*)carve((size_t)n * 4);
    int*   esrc   = (int*)carve((size_t)E * 4);
    uint2* binned = (uint2*)carve((size_t)E * 8);
    int*   H      = (int*)carve((size_t)HN * 4);
    int*   Hscan  = (int*)carve((size_t)HN * 4);
    float* sums   = (float*)carve(512 * 4);   // [sum1|sq1|sum2|sq2]
    float* bnsc   = (float*)carve(512 * 4);   // [scale1|shift1|scale2|shift2]
    int*   bsum   = (int*)carve(1024 * 4);
    unsigned int* xwb = (unsigned int*)carve((size_t)n * 128 * 2);  // gemm out (bf16 packed, pre-scaled by dinv)
    float* bufB   = (float*)carve((size_t)n * 128 * 4);             // agg out (fp32)

    hipMemsetAsync(sums, 0, 512 * 4, stream);

    int sbH = (HN + 1023) / 1024;    // 49 <= 256

    // bucketed CSR build (single LDS-atomic build kernel; no global N-scan)
    hist_kernel<<<G, 256, 0, stream>>>(dstv, H, E, G);
    blocksum_kernel<<<sbH, 256, 0, stream>>>(H, bsum, HN);
    scan_bsum_kernel<<<1, 256, 0, stream>>>(bsum, sbH);
    scan_write1_kernel<<<sbH, 256, 0, stream>>>(H, bsum, Hscan, HN);
    bin_scatter_kernel<<<G, 256, 0, stream>>>(srcv, dstv, Hscan, binned, E, G);
    bucket_build_kernel<<<NB, 256, 0, stream>>>(binned, Hscan, cnt, rowptr, dinv, esrc, E, G, n);

    int gb = (n + 63) / 64;
    int ab = (n + 3) / 4;   // one wave per node

    // layer 1: gcn(x, W1) + b1
    gemm_kernel<128><<<gb, 256, 0, stream>>>(x, W1, nullptr, nullptr, dinv, xwb, n);
    agg128_kernel<<<ab, 256, 0, stream>>>(xwb, rowptr, cnt, esrc, dinv, b1, bufB, n);
    bn_stats_kernel<<<512, 256, 0, stream>>>(bufB, sums, n);
    bn_finalize_kernel<<<1, 128, 0, stream>>>(sums, g1, be1, bnsc, bnsc + 128, n);

    // layer 2: gcn(relu(bn1(h)), W2) + b2   (bn1+relu fused into gemm staging)
    gemm_kernel<128><<<gb, 256, 0, stream>>>(bufB, W2, bnsc, bnsc + 128, dinv, xwb, n);
    agg128_kernel<<<ab, 256, 0, stream>>>(xwb, rowptr, cnt, esrc, dinv, b2, bufB, n);
    bn_stats_kernel<<<512, 256, 0, stream>>>(bufB, sums + 256, n);
    bn_finalize_kernel<<<1, 128, 0, stream>>>(sums + 256, g2, be2, bnsc + 256, bnsc + 384, n);

    // layer 3: gcn(relu(bn2(h)), W3) + b3  -> d_out
    gemm_kernel<64><<<gb, 256, 0, stream>>>(bufB, W3, bnsc + 256, bnsc + 384, dinv, xwb, n);
    agg64_kernel<<<ab, 256, 0, stream>>>(xwb, rowptr, cnt, esrc, dinv, b3, (float*)d_out, n);
}

// Round 2
// 493.915 us; speedup vs baseline: 1.2216x; 1.1442x over previous
//
#include <hip/hip_runtime.h>
#include <cstdint>
#include <cstddef>

#define BN_EPS 1e-5f
#define BKT 256        // buckets (dst>>9), 512 nodes each; 100000>>9 = 195 -> 196 used
#define BSH 9
#define CHUNK 8192     // edges per block in hist/scatter

typedef __attribute__((ext_vector_type(8))) short bf16x8;   // 8 bf16 = 4 VGPRs
typedef __attribute__((ext_vector_type(4))) float f32x4;    // MFMA acc

// ---- manual bf16 helpers (hip_bf16.h intrinsics unavailable in this ROCm) ----
__device__ __forceinline__ unsigned int f32_to_bf16_rne(float f) {
    unsigned int u = __float_as_uint(f);
    u += 0x7FFFu + ((u >> 16) & 1u);
    return u >> 16;
}
__device__ __forceinline__ unsigned int pack_bf16x2(float a, float b) {
    return f32_to_bf16_rne(a) | (f32_to_bf16_rne(b) << 16);
}
__device__ __forceinline__ float bf16_lo(unsigned int p) { return __uint_as_float(p << 16); }
__device__ __forceinline__ float bf16_hi(unsigned int p) { return __uint_as_float(p & 0xFFFF0000u); }

// ---------------- bucketed CSR build ----------------
// Phase 1: per-(bucket,block) histogram H[b*G+g]
__global__ void hist_kernel(const int* __restrict__ dst, int* __restrict__ H, int e, int G) {
    __shared__ int h[BKT];
    int t = threadIdx.x, g = blockIdx.x;
    h[t] = 0;
    __syncthreads();
    int base = g * CHUNK;
#pragma unroll
    for (int i = 0; i < CHUNK / 256; i++) {
        int idx = base + i * 256 + t;
        if (idx < e) atomicAdd(&h[dst[idx] >> BSH], 1);
    }
    __syncthreads();
    H[t * G + g] = h[t];
}

// Phase 3: scatter (src,dst) into bucket-contiguous binned array.
__global__ void bin_scatter_kernel(const int* __restrict__ src, const int* __restrict__ dst,
                                   const int* __restrict__ Hscan, uint2* __restrict__ binned,
                                   int e, int G) {
    __shared__ int cur[BKT];
    int t = threadIdx.x, g = blockIdx.x;
    cur[t] = Hscan[t * G + g];
    __syncthreads();
    int base = g * CHUNK;
#pragma unroll
    for (int i = 0; i < CHUNK / 256; i++) {
        int idx = base + i * 256 + t;
        if (idx < e) {
            int s = src[idx], d = dst[idx];
            int pos = atomicAdd(&cur[d >> BSH], 1);
            uint2 v; v.x = (unsigned)s; v.y = (unsigned)d;
            binned[pos] = v;
        }
    }
}

// Phase 4: one block per bucket (512 nodes). Count degrees, local scan,
// write cnt/rowptr/dinv, then fill esrc -- all cursors/counts in LDS.
__global__ __launch_bounds__(256) void bucket_build_kernel(const uint2* __restrict__ binned,
                                                           const int* __restrict__ Hscan,
                                                           int* __restrict__ cnt,
                                                           int* __restrict__ rowptr,
                                                           float* __restrict__ dinv,
                                                           int* __restrict__ esrc,
                                                           int e, int G, int n) {
    __shared__ int lcnt[512], lexc[512], ssum[256];
    const int t = threadIdx.x;
    const int b = blockIdx.x;
    const int start = Hscan[b * G];
    const int end = (b == BKT - 1) ? e : Hscan[(b + 1) * G];

    lcnt[t] = 0; lcnt[t + 256] = 0;
    __syncthreads();
    for (int i = start + t; i < end; i += 256)
        atomicAdd(&lcnt[binned[i].y & 511], 1);
    __syncthreads();

    int a0 = lcnt[2 * t], a1 = lcnt[2 * t + 1];
    ssum[t] = a0 + a1;
    __syncthreads();
    for (int off = 1; off < 256; off <<= 1) {
        int v = (t >= off) ? ssum[t - off] : 0;
        __syncthreads();
        ssum[t] += v;
        __syncthreads();
    }
    int excl = (t == 0) ? 0 : ssum[t - 1];
    lexc[2 * t] = excl;
    lexc[2 * t + 1] = excl + a0;
    __syncthreads();

    int nodebase = b << BSH;
#pragma unroll
    for (int j2 = 0; j2 < 2; j2++) {
        int j = 2 * t + j2;
        int node = nodebase + j;
        if (node < n) {
            int c = lcnt[j];
            cnt[node] = c;
            rowptr[node] = start + lexc[j];
            dinv[node] = rsqrtf((float)(c + 1));
        }
    }
    __syncthreads();

    for (int i = start + t; i < end; i += 256) {
        uint2 ed = binned[i];
        int pos = start + atomicAdd(&lexc[ed.y & 511], 1);
        esrc[pos] = (int)ed.x;
    }
}

// ---- scan helpers for H (bucket-major (bucket,block) histogram) ----

__global__ void blocksum_kernel(const int* __restrict__ in, int* __restrict__ bsum, int n) {
    int t = threadIdx.x;
    int base = blockIdx.x * 1024 + t * 4;
    int s = 0;
    if (base + 3 < n) {
        int4 v = *(const int4*)&in[base];
        s = v.x + v.y + v.z + v.w;
    } else {
        for (int j = 0; j < 4; j++) if (base + j < n) s += in[base + j];
    }
    __shared__ int ls[256];
    ls[t] = s;
    __syncthreads();
    for (int off = 128; off > 0; off >>= 1) {
        if (t < off) ls[t] += ls[t + off];
        __syncthreads();
    }
    if (t == 0) bsum[blockIdx.x] = ls[0];
}

__global__ void scan_bsum_kernel(int* __restrict__ bsum, int nb) {
    int t = threadIdx.x;
    __shared__ int ls[256];
    int v = (t < nb) ? bsum[t] : 0;
    ls[t] = v;
    __syncthreads();
    for (int off = 1; off < 256; off <<= 1) {
        int p = (t >= off) ? ls[t - off] : 0;
        __syncthreads();
        ls[t] += p;
        __syncthreads();
    }
    if (t < nb) bsum[t] = ls[t] - v;   // inclusive -> exclusive
}

__global__ void scan_write1_kernel(const int* __restrict__ in, const int* __restrict__ bsum,
                                   int* __restrict__ out, int n) {
    int t = threadIdx.x;
    int base = blockIdx.x * 1024 + t * 4;
    int v[4];
    int s = 0;
    if (base + 3 < n) {
        int4 q = *(const int4*)&in[base];
        v[0] = q.x; v[1] = q.y; v[2] = q.z; v[3] = q.w;
        s = q.x + q.y + q.z + q.w;
    } else {
        for (int j = 0; j < 4; j++) { v[j] = (base + j < n) ? in[base + j] : 0; s += v[j]; }
    }
    __shared__ int ls[256];
    ls[t] = s;
    __syncthreads();
    for (int off = 1; off < 256; off <<= 1) {
        int p = (t >= off) ? ls[t - off] : 0;
        __syncthreads();
        ls[t] += p;
        __syncthreads();
    }
    int run = bsum[blockIdx.x] + ls[t] - s;
    if (base + 3 < n) {
        int4 r; r.x = run; r.y = run + v[0]; r.z = run + v[0] + v[1]; r.w = run + v[0] + v[1] + v[2];
        *(int4*)&out[base] = r;
    } else {
        for (int j = 0; j < 4; j++) {
            if (base + j < n) out[base + j] = run;
            run += v[j];
        }
    }
}

// ---------------- W fragment prep: W[128][OUTC] fp32 -> hi/lo bf16 MFMA B-fragments ----
// Layout: slot = (ct*4 + kc)*64 + lane; each slot holds 8 bf16 (16B):
//   element j: W[kc*32 + (lane>>4)*8 + j][ct*16 + (lane&15)]
// hi = bf16_rne(w), lo = bf16_rne(w - hi)  (split-precision operands).

template <int OUTC>
__global__ void wprep_kernel(const float* __restrict__ W,
                             uint4* __restrict__ whi, uint4* __restrict__ wlo) {
    constexpr int NSLOT = (OUTC / 16) * 4 * 64;
    int slot = blockIdx.x * 256 + threadIdx.x;
    if (slot >= NSLOT) return;
    int l  = slot & 63;
    int kc = (slot >> 6) & 3;
    int ct = slot >> 8;
    int c  = ct * 16 + (l & 15);
    int k0 = kc * 32 + (l >> 4) * 8;
    unsigned hi[4], lo[4];
#pragma unroll
    for (int jj = 0; jj < 4; jj++) {
        float v0 = W[(size_t)(k0 + 2 * jj) * OUTC + c];
        float v1 = W[(size_t)(k0 + 2 * jj + 1) * OUTC + c];
        unsigned h0 = f32_to_bf16_rne(v0), h1 = f32_to_bf16_rne(v1);
        float l0 = v0 - __uint_as_float(h0 << 16);
        float l1 = v1 - __uint_as_float(h1 << 16);
        hi[jj] = h0 | (h1 << 16);
        lo[jj] = pack_bf16x2(l0, l1);
    }
    uint4 uh; uh.x = hi[0]; uh.y = hi[1]; uh.z = hi[2]; uh.w = hi[3];
    uint4 ul; ul.x = lo[0]; ul.y = lo[1]; ul.z = lo[2]; ul.w = lo[3];
    whi[slot] = uh;
    wlo[slot] = ul;
}

// ---------------- GEMM via bf16 MFMA (fp32-equivalent via hi/lo split) ----------------
// Y[n,OUTC](bf16, pre-scaled by dinv[row]) = dinv[r] * act(X[n,128]) @ W[128,OUTC]
// act = BN(scale,shift)+ReLU when scale!=nullptr, else identity.
// Per block: 64 rows x OUTC cols. 4 waves; wave w owns col-tiles {w*CTW .. }.
// Operands SWAPPED in mfma (W-frag as A, X-frag as B) so D is row-major per
// lane: lane holds 4 consecutive output cols of one row -> uint2 store.

template <int OUTC>
__global__ __launch_bounds__(256) void gemm_kernel(const float* __restrict__ X,
                                                   const uint4* __restrict__ whi,
                                                   const uint4* __restrict__ wlo,
                                                   const float* __restrict__ scale,
                                                   const float* __restrict__ shift,
                                                   const float* __restrict__ dinv,
                                                   unsigned int* __restrict__ Y, int n) {
    constexpr int NCT = OUTC / 16;
    constexpr int CTW = NCT / 4;   // col-tiles per wave (2 for OUTC=128, 1 for 64)
    __shared__ __align__(16) unsigned short lAhi[64 * 128];  // 16 KB, XOR-swizzled
    __shared__ __align__(16) unsigned short lAlo[64 * 128];  // 16 KB
    __shared__ float ldv[64];
    const int t = threadIdx.x;
    const int base = blockIdx.x * 64;
    const int lane = t & 63;
    const int w = t >> 6;
    const bool bn = (scale != nullptr);

    if (t < 64) { int r = base + t; ldv[t] = (r < n) ? dinv[r] : 0.0f; }

    // B fragments (registers, whole kernel): CTW x 4 kc x {hi,lo}
    bf16x8 bhi[CTW][4], blo[CTW][4];
#pragma unroll
    for (int c = 0; c < CTW; c++) {
        int ct = w * CTW + c;
#pragma unroll
        for (int kc = 0; kc < 4; kc++) {
            int slot = (ct * 4 + kc) * 64 + lane;
            bhi[c][kc] = *reinterpret_cast<const bf16x8*>(whi + slot);
            blo[c][kc] = *reinterpret_cast<const bf16x8*>(wlo + slot);
        }
    }

    // Stage A: coalesced fp32 loads, fused BN+ReLU, hi/lo bf16 split, swizzled LDS.
    const int col4 = (t & 31) * 4;
    float4 sc4, sh4;
    if (bn) {
        sc4 = *(const float4*)&scale[col4];
        sh4 = *(const float4*)&shift[col4];
    }
#pragma unroll
    for (int i = 0; i < 8; i++) {
        int row = i * 8 + (t >> 5);
        int r = base + row;
        float4 xv = make_float4(0.f, 0.f, 0.f, 0.f);
        if (r < n) xv = *(const float4*)&X[(size_t)r * 128 + col4];
        if (bn) {
            xv.x = fmaxf(fmaf(xv.x, sc4.x, sh4.x), 0.0f);
            xv.y = fmaxf(fmaf(xv.y, sc4.y, sh4.y), 0.0f);
            xv.z = fmaxf(fmaf(xv.z, sc4.z, sh4.z), 0.0f);
            xv.w = fmaxf(fmaf(xv.w, sc4.w, sh4.w), 0.0f);
        }
        unsigned h0 = f32_to_bf16_rne(xv.x), h1 = f32_to_bf16_rne(xv.y);
        unsigned h2 = f32_to_bf16_rne(xv.z), h3 = f32_to_bf16_rne(xv.w);
        float l0 = xv.x - __uint_as_float(h0 << 16);
        float l1 = xv.y - __uint_as_float(h1 << 16);
        float l2 = xv.z - __uint_as_float(h2 << 16);
        float l3 = xv.w - __uint_as_float(h3 << 16);
        uint2 ph; ph.x = h0 | (h1 << 16); ph.y = h2 | (h3 << 16);
        uint2 pl; pl.x = pack_bf16x2(l0, l1); pl.y = pack_bf16x2(l2, l3);
        int off = row * 256 + ((col4 * 2) ^ ((row & 7) << 4));
        *(uint2*)((char*)lAhi + off) = ph;
        *(uint2*)((char*)lAlo + off) = pl;
    }
    __syncthreads();

    // Compute: 4 row-tiles of 16; per (rt,kc): 2 LDS frag reads + 3*CTW MFMAs.
    const int arow = lane & 15;
    const int kb16 = (lane >> 4) * 16;
#pragma unroll
    for (int rt = 0; rt < 4; rt++) {
        f32x4 acc[CTW];
#pragma unroll
        for (int c = 0; c < CTW; c++) acc[c] = (f32x4){0.f, 0.f, 0.f, 0.f};
        int row = rt * 16 + arow;
        int rb = row * 256;
        int sw = (row & 7) << 4;
#pragma unroll
        for (int kc = 0; kc < 4; kc++) {
            int off = rb + ((kc * 64 + kb16) ^ sw);
            bf16x8 ah = *(const bf16x8*)((const char*)lAhi + off);
            bf16x8 al = *(const bf16x8*)((const char*)lAlo + off);
#pragma unroll
            for (int c = 0; c < CTW; c++) {
                acc[c] = __builtin_amdgcn_mfma_f32_16x16x32_bf16(bhi[c][kc], ah, acc[c], 0, 0, 0);
                acc[c] = __builtin_amdgcn_mfma_f32_16x16x32_bf16(blo[c][kc], ah, acc[c], 0, 0, 0);
                acc[c] = __builtin_amdgcn_mfma_f32_16x16x32_bf16(bhi[c][kc], al, acc[c], 0, 0, 0);
            }
        }
        int r = base + row;
        if (r < n) {
            float dv = ldv[row];
#pragma unroll
            for (int c = 0; c < CTW; c++) {
                int ct = w * CTW + c;
                uint2 o;
                o.x = pack_bf16x2(acc[c][0] * dv, acc[c][1] * dv);
                o.y = pack_bf16x2(acc[c][2] * dv, acc[c][3] * dv);
                *(uint2*)&Y[(size_t)r * (OUTC / 2) + ct * 8 + (lane >> 4) * 2] = o;
            }
        }
    }
}

// ---------------- aggregation (128 cols): one wave per node ----------------
// xw rows are pre-scaled by dinv[src]. out[d] = dinv[d]*(sum xw'[s] + xw'[d]) + b.
// Fully predicated 8-edge batches (clamped index -> no serial tail, no extra
// cache lines), esrc batch software-pipelined one batch ahead, node-uniform
// values readfirstlane'd so edge-list loads take the scalar path.

__global__ __launch_bounds__(256) void agg128_kernel(const unsigned int* __restrict__ xw,
                                                     const int* __restrict__ rowptr,
                                                     const int* __restrict__ cnt,
                                                     const int* __restrict__ esrc,
                                                     const float* __restrict__ dinv,
                                                     const float* __restrict__ bias,
                                                     float* __restrict__ out, int n) {
    int gid = blockIdx.x * 256 + threadIdx.x;
    int node = __builtin_amdgcn_readfirstlane(gid >> 6);
    if (node >= n) return;
    int lane = threadIdx.x & 63;
    float di = dinv[node];
    int beg = __builtin_amdgcn_readfirstlane(rowptr[node]);
    int cv  = __builtin_amdgcn_readfirstlane(cnt[node]);
    int last = beg + cv - 1;

    unsigned int ap = xw[(size_t)node * 64 + lane];
    float ax = bf16_lo(ap), ay = bf16_hi(ap);

    int nb = (cv + 7) >> 3;
    int s[8], sn[8];
    if (nb > 0) {
#pragma unroll
        for (int j = 0; j < 8; j++) {
            int idx = beg + j;
            s[j] = esrc[idx <= last ? idx : last];
        }
    }
    for (int b = 0; b < nb; b++) {
        int ebase = beg + b * 8;
        if (b + 1 < nb) {
#pragma unroll
            for (int j = 0; j < 8; j++) {
                int idx = ebase + 8 + j;
                sn[j] = esrc[idx <= last ? idx : last];
            }
        }
        unsigned int v[8];
#pragma unroll
        for (int j = 0; j < 8; j++) v[j] = xw[(size_t)s[j] * 64 + lane];
        int rem = last - ebase;   // valid lanes: j <= rem (wave-uniform)
#pragma unroll
        for (int j = 0; j < 8; j++) {
            float m = (j <= rem) ? 1.0f : 0.0f;
            ax = fmaf(m, bf16_lo(v[j]), ax);
            ay = fmaf(m, bf16_hi(v[j]), ay);
        }
        if (b + 1 < nb) {
#pragma unroll
            for (int j = 0; j < 8; j++) s[j] = sn[j];
        }
    }
    float2 bv = ((const float2*)bias)[lane];
    float2 o; o.x = fmaf(di, ax, bv.x); o.y = fmaf(di, ay, bv.y);
    ((float2*)(out + (size_t)node * 128))[lane] = o;
}

// ---------------- aggregation (64-col output layer) ----------------

__global__ __launch_bounds__(256) void agg64_kernel(const unsigned int* __restrict__ xw,
                                                    const int* __restrict__ rowptr,
                                                    const int* __restrict__ cnt,
                                                    const int* __restrict__ esrc,
                                                    const float* __restrict__ dinv,
                                                    const float* __restrict__ bias,
                                                    float* __restrict__ out, int n) {
    int gid = blockIdx.x * 256 + threadIdx.x;
    int node = __builtin_amdgcn_readfirstlane(gid >> 6);
    if (node >= n) return;
    int lane = threadIdx.x & 63;
    int col = lane >> 1;
    bool hi = (lane & 1) != 0;
    float di = dinv[node];
    int beg = __builtin_amdgcn_readfirstlane(rowptr[node]);
    int cv  = __builtin_amdgcn_readfirstlane(cnt[node]);
    int last = beg + cv - 1;

    unsigned int ap = xw[(size_t)node * 32 + col];
    float acc = hi ? bf16_hi(ap) : bf16_lo(ap);

    int nb = (cv + 7) >> 3;
    int s[8], sn[8];
    if (nb > 0) {
#pragma unroll
        for (int j = 0; j < 8; j++) {
            int idx = beg + j;
            s[j] = esrc[idx <= last ? idx : last];
        }
    }
    for (int b = 0; b < nb; b++) {
        int ebase = beg + b * 8;
        if (b + 1 < nb) {
#pragma unroll
            for (int j = 0; j < 8; j++) {
                int idx = ebase + 8 + j;
                sn[j] = esrc[idx <= last ? idx : last];
            }
        }
        unsigned int v[8];
#pragma unroll
        for (int j = 0; j < 8; j++) v[j] = xw[(size_t)s[j] * 32 + col];
        int rem = last - ebase;
#pragma unroll
        for (int j = 0; j < 8; j++) {
            float m = (j <= rem) ? 1.0f : 0.0f;
            float vf = hi ? bf16_hi(v[j]) : bf16_lo(v[j]);
            acc = fmaf(m, vf, acc);
        }
        if (b + 1 < nb) {
#pragma unroll
            for (int j = 0; j < 8; j++) s[j] = sn[j];
        }
    }
    out[(size_t)node * 64 + lane] = fmaf(di, acc, bias[lane]);
}

// ---------------- BatchNorm (training-mode, biased var) ----------------

__global__ void bn_stats_kernel(const float* __restrict__ h, float* __restrict__ sums, int n) {
    int c = threadIdx.x & 127;
    int half = threadIdx.x >> 7;
    float s = 0.0f, q = 0.0f;
    for (int r = blockIdx.x * 2 + half; r < n; r += gridDim.x * 2) {
        float v = h[(size_t)r * 128 + c];
        s += v;
        q = fmaf(v, v, q);
    }
    __shared__ float ls[256], lq[256];
    ls[threadIdx.x] = s; lq[threadIdx.x] = q;
    __syncthreads();
    if (half == 0) {
        s += ls[c + 128];
        q += lq[c + 128];
        atomicAdd(&sums[c], s);
        atomicAdd(&sums[128 + c], q);
    }
}

__global__ void bn_finalize_kernel(const float* __restrict__ sums, const float* __restrict__ g,
                                   const float* __restrict__ be, float* __restrict__ scale,
                                   float* __restrict__ shift, int n) {
    int c = threadIdx.x;  // 128 threads
    float inv_n = 1.0f / (float)n;
    float mean = sums[c] * inv_n;
    float var = sums[128 + c] * inv_n - mean * mean;
    float rstd = rsqrtf(var + BN_EPS);
    float sc = rstd * g[c];
    scale[c] = sc;
    shift[c] = be[c] - mean * sc;
}

// ---------------- launch ----------------

extern "C" void kernel_launch(void* const* d_in, const int* in_sizes, int n_in,
                              void* d_out, int out_size, void* d_ws, size_t ws_size,
                              hipStream_t stream) {
    const float* x   = (const float*)d_in[0];
    const int*   ei  = (const int*)d_in[1];
    const float* W1  = (const float*)d_in[2];
    const float* b1  = (const float*)d_in[3];
    const float* g1  = (const float*)d_in[4];
    const float* be1 = (const float*)d_in[5];
    const float* W2  = (const float*)d_in[6];
    const float* b2  = (const float*)d_in[7];
    const float* g2  = (const float*)d_in[8];
    const float* be2 = (const float*)d_in[9];
    const float* W3  = (const float*)d_in[10];
    const float* b3  = (const float*)d_in[11];

    const int n = in_sizes[0] / 128;
    const int E = in_sizes[1] / 2;
    const int* srcv = ei;
    const int* dstv = ei + E;

    const int G = (E + CHUNK - 1) / CHUNK;      // hist/scatter blocks (196)
    const int HN = BKT * G;                      // H matrix elements (50176)
    const int NB = (n + 511) >> 9;               // used buckets (196)

    char* p = (char*)d_ws;
    auto carve = [&](size_t bytes) -> char* {
        char* q = p;
        p += (bytes + 255) & ~(size_t)255;
        return q;
    };
    int*   cnt    = (int*)carve((size_t)n * 4);
    int*   rowptr = (int*)carve((size_t)n * 4);
    float* dinv   = (float*)carve((size_t)n * 4);
    int*   esrc   = (int*)carve((size_t)E * 4);
    uint2* binned = (uint2*)carve((size_t)E * 8);
    int*   H      = (int*)carve((size_t)HN * 4);
    int*   Hscan  = (int*)carve((size_t)HN * 4);
    float* sums   = (float*)carve(512 * 4);   // [sum1|sq1|sum2|sq2]
    float* bnsc   = (float*)carve(512 * 4);   // [scale1|shift1|scale2|shift2]
    int*   bsum   = (int*)carve(1024 * 4);
    uint4* w1hi   = (uint4*)carve(2048 * 16); // W-frag arrays (hi/lo bf16)
    uint4* w1lo   = (uint4*)carve(2048 * 16);
    uint4* w2hi   = (uint4*)carve(2048 * 16);
    uint4* w2lo   = (uint4*)carve(2048 * 16);
    uint4* w3hi   = (uint4*)carve(1024 * 16);
    uint4* w3lo   = (uint4*)carve(1024 * 16);
    unsigned int* xwb = (unsigned int*)carve((size_t)n * 128 * 2);  // gemm out (bf16 packed, pre-scaled by dinv)
    float* bufB   = (float*)carve((size_t)n * 128 * 4);             // agg out (fp32)

    hipMemsetAsync(sums, 0, 512 * 4, stream);

    int sbH = (HN + 1023) / 1024;    // 49 <= 256

    // W fragment prep (no deps; overlaps CSR build region)
    wprep_kernel<128><<<8, 256, 0, stream>>>(W1, w1hi, w1lo);
    wprep_kernel<128><<<8, 256, 0, stream>>>(W2, w2hi, w2lo);
    wprep_kernel<64><<<4, 256, 0, stream>>>(W3, w3hi, w3lo);

    // bucketed CSR build (single LDS-atomic build kernel; no global N-scan)
    hist_kernel<<<G, 256, 0, stream>>>(dstv, H, E, G);
    blocksum_kernel<<<sbH, 256, 0, stream>>>(H, bsum, HN);
    scan_bsum_kernel<<<1, 256, 0, stream>>>(bsum, sbH);
    scan_write1_kernel<<<sbH, 256, 0, stream>>>(H, bsum, Hscan, HN);
    bin_scatter_kernel<<<G, 256, 0, stream>>>(srcv, dstv, Hscan, binned, E, G);
    bucket_build_kernel<<<NB, 256, 0, stream>>>(binned, Hscan, cnt, rowptr, dinv, esrc, E, G, n);

    int gb = (n + 63) / 64;
    int ab = (n + 3) / 4;   // one wave per node

    // layer 1: gcn(x, W1) + b1
    gemm_kernel<128><<<gb, 256, 0, stream>>>(x, w1hi, w1lo, nullptr, nullptr, dinv, xwb, n);
    agg128_kernel<<<ab, 256, 0, stream>>>(xwb, rowptr, cnt, esrc, dinv, b1, bufB, n);
    bn_stats_kernel<<<512, 256, 0, stream>>>(bufB, sums, n);
    bn_finalize_kernel<<<1, 128, 0, stream>>>(sums, g1, be1, bnsc, bnsc + 128, n);

    // layer 2: gcn(relu(bn1(h)), W2) + b2   (bn1+relu fused into gemm staging)
    gemm_kernel<128><<<gb, 256, 0, stream>>>(bufB, w2hi, w2lo, bnsc, bnsc + 128, dinv, xwb, n);
    agg128_kernel<<<ab, 256, 0, stream>>>(xwb, rowptr, cnt, esrc, dinv, b2, bufB, n);
    bn_stats_kernel<<<512, 256, 0, stream>>>(bufB, sums + 256, n);
    bn_finalize_kernel<<<1, 128, 0, stream>>>(sums + 256, g2, be2, bnsc + 256, bnsc + 384, n);

    // layer 3: gcn(relu(bn2(h)), W3) + b3  -> d_out
    gemm_kernel<64><<<gb, 256, 0, stream>>>(bufB, w3hi, w3lo, bnsc + 256, bnsc + 384, dinv, xwb, n);
    agg64_kernel<<<ab, 256, 0, stream>>>(xwb, rowptr, cnt, esrc, dinv, b3, (float*)d_out, n);
}

// Round 3
// 471.351 us; speedup vs baseline: 1.2801x; 1.0479x over previous
//
#include <hip/hip_runtime.h>
#include <cstdint>
#include <cstddef>

#define BN_EPS 1e-5f
#define BKT 256        // buckets (dst>>9), 512 nodes each; 100000>>9 = 195 -> 196 used
#define BSH 9
#define CHUNK 8192     // edges per block in hist/scatter

typedef __attribute__((ext_vector_type(8))) short bf16x8;   // 8 bf16 = 4 VGPRs
typedef __attribute__((ext_vector_type(4))) float f32x4;    // MFMA acc

// ---- manual bf16 helpers (hip_bf16.h intrinsics unavailable in this ROCm) ----
__device__ __forceinline__ unsigned int f32_to_bf16_rne(float f) {
    unsigned int u = __float_as_uint(f);
    u += 0x7FFFu + ((u >> 16) & 1u);
    return u >> 16;
}
__device__ __forceinline__ unsigned int pack_bf16x2(float a, float b) {
    return f32_to_bf16_rne(a) | (f32_to_bf16_rne(b) << 16);
}
__device__ __forceinline__ float bf16_lo(unsigned int p) { return __uint_as_float(p << 16); }
__device__ __forceinline__ float bf16_hi(unsigned int p) { return __uint_as_float(p & 0xFFFF0000u); }

// ---------------- bucketed CSR build ----------------
// Phase 1: per-(bucket,block) histogram H[b*G+g]
__global__ void hist_kernel(const int* __restrict__ dst, int* __restrict__ H, int e, int G) {
    __shared__ int h[BKT];
    int t = threadIdx.x, g = blockIdx.x;
    h[t] = 0;
    __syncthreads();
    int base = g * CHUNK;
#pragma unroll
    for (int i = 0; i < CHUNK / 256; i++) {
        int idx = base + i * 256 + t;
        if (idx < e) atomicAdd(&h[dst[idx] >> BSH], 1);
    }
    __syncthreads();
    H[t * G + g] = h[t];
}

// Phase 3: scatter (src,dst) into bucket-contiguous binned array.
__global__ void bin_scatter_kernel(const int* __restrict__ src, const int* __restrict__ dst,
                                   const int* __restrict__ Hscan, uint2* __restrict__ binned,
                                   int e, int G) {
    __shared__ int cur[BKT];
    int t = threadIdx.x, g = blockIdx.x;
    cur[t] = Hscan[t * G + g];
    __syncthreads();
    int base = g * CHUNK;
#pragma unroll
    for (int i = 0; i < CHUNK / 256; i++) {
        int idx = base + i * 256 + t;
        if (idx < e) {
            int s = src[idx], d = dst[idx];
            int pos = atomicAdd(&cur[d >> BSH], 1);
            uint2 v; v.x = (unsigned)s; v.y = (unsigned)d;
            binned[pos] = v;
        }
    }
}

// Phase 4: one block per bucket (512 nodes). Count degrees, local scan,
// write cnt/rowptr/dinv, then fill esrc -- all cursors/counts in LDS.
__global__ __launch_bounds__(256) void bucket_build_kernel(const uint2* __restrict__ binned,
                                                           const int* __restrict__ Hscan,
                                                           int* __restrict__ cnt,
                                                           int* __restrict__ rowptr,
                                                           float* __restrict__ dinv,
                                                           int* __restrict__ esrc,
                                                           int e, int G, int n) {
    __shared__ int lcnt[512], lexc[512], ssum[256];
    const int t = threadIdx.x;
    const int b = blockIdx.x;
    const int start = Hscan[b * G];
    const int end = (b == BKT - 1) ? e : Hscan[(b + 1) * G];

    lcnt[t] = 0; lcnt[t + 256] = 0;
    __syncthreads();
    for (int i = start + t; i < end; i += 256)
        atomicAdd(&lcnt[binned[i].y & 511], 1);
    __syncthreads();

    int a0 = lcnt[2 * t], a1 = lcnt[2 * t + 1];
    ssum[t] = a0 + a1;
    __syncthreads();
    for (int off = 1; off < 256; off <<= 1) {
        int v = (t >= off) ? ssum[t - off] : 0;
        __syncthreads();
        ssum[t] += v;
        __syncthreads();
    }
    int excl = (t == 0) ? 0 : ssum[t - 1];
    lexc[2 * t] = excl;
    lexc[2 * t + 1] = excl + a0;
    __syncthreads();

    int nodebase = b << BSH;
#pragma unroll
    for (int j2 = 0; j2 < 2; j2++) {
        int j = 2 * t + j2;
        int node = nodebase + j;
        if (node < n) {
            int c = lcnt[j];
            cnt[node] = c;
            rowptr[node] = start + lexc[j];
            dinv[node] = rsqrtf((float)(c + 1));
        }
    }
    __syncthreads();

    for (int i = start + t; i < end; i += 256) {
        uint2 ed = binned[i];
        int pos = start + atomicAdd(&lexc[ed.y & 511], 1);
        esrc[pos] = (int)ed.x;
    }
}

// ---- scan helpers for H (bucket-major (bucket,block) histogram) ----

__global__ void blocksum_kernel(const int* __restrict__ in, int* __restrict__ bsum, int n) {
    int t = threadIdx.x;
    int base = blockIdx.x * 1024 + t * 4;
    int s = 0;
    if (base + 3 < n) {
        int4 v = *(const int4*)&in[base];
        s = v.x + v.y + v.z + v.w;
    } else {
        for (int j = 0; j < 4; j++) if (base + j < n) s += in[base + j];
    }
    __shared__ int ls[256];
    ls[t] = s;
    __syncthreads();
    for (int off = 128; off > 0; off >>= 1) {
        if (t < off) ls[t] += ls[t + off];
        __syncthreads();
    }
    if (t == 0) bsum[blockIdx.x] = ls[0];
}

__global__ void scan_bsum_kernel(int* __restrict__ bsum, int nb) {
    int t = threadIdx.x;
    __shared__ int ls[256];
    int v = (t < nb) ? bsum[t] : 0;
    ls[t] = v;
    __syncthreads();
    for (int off = 1; off < 256; off <<= 1) {
        int p = (t >= off) ? ls[t - off] : 0;
        __syncthreads();
        ls[t] += p;
        __syncthreads();
    }
    if (t < nb) bsum[t] = ls[t] - v;   // inclusive -> exclusive
}

__global__ void scan_write1_kernel(const int* __restrict__ in, const int* __restrict__ bsum,
                                   int* __restrict__ out, int n) {
    int t = threadIdx.x;
    int base = blockIdx.x * 1024 + t * 4;
    int v[4];
    int s = 0;
    if (base + 3 < n) {
        int4 q = *(const int4*)&in[base];
        v[0] = q.x; v[1] = q.y; v[2] = q.z; v[3] = q.w;
        s = q.x + q.y + q.z + q.w;
    } else {
        for (int j = 0; j < 4; j++) { v[j] = (base + j < n) ? in[base + j] : 0; s += v[j]; }
    }
    __shared__ int ls[256];
    ls[t] = s;
    __syncthreads();
    for (int off = 1; off < 256; off <<= 1) {
        int p = (t >= off) ? ls[t - off] : 0;
        __syncthreads();
        ls[t] += p;
        __syncthreads();
    }
    int run = bsum[blockIdx.x] + ls[t] - s;
    if (base + 3 < n) {
        int4 r; r.x = run; r.y = run + v[0]; r.z = run + v[0] + v[1]; r.w = run + v[0] + v[1] + v[2];
        *(int4*)&out[base] = r;
    } else {
        for (int j = 0; j < 4; j++) {
            if (base + j < n) out[base + j] = run;
            run += v[j];
        }
    }
}

// ---------------- W fragment prep: W[128][OUTC] fp32 -> hi/lo bf16 MFMA B-fragments ----
// Layout: slot = (ct*4 + kc)*64 + lane; each slot holds 8 bf16 (16B):
//   element j: W[kc*32 + (lane>>4)*8 + j][ct*16 + (lane&15)]
// hi = bf16_rne(w), lo = bf16_rne(w - hi)  (split-precision operands).

template <int OUTC>
__global__ void wprep_kernel(const float* __restrict__ W,
                             uint4* __restrict__ whi, uint4* __restrict__ wlo) {
    constexpr int NSLOT = (OUTC / 16) * 4 * 64;
    int slot = blockIdx.x * 256 + threadIdx.x;
    if (slot >= NSLOT) return;
    int l  = slot & 63;
    int kc = (slot >> 6) & 3;
    int ct = slot >> 8;
    int c  = ct * 16 + (l & 15);
    int k0 = kc * 32 + (l >> 4) * 8;
    unsigned hi[4], lo[4];
#pragma unroll
    for (int jj = 0; jj < 4; jj++) {
        float v0 = W[(size_t)(k0 + 2 * jj) * OUTC + c];
        float v1 = W[(size_t)(k0 + 2 * jj + 1) * OUTC + c];
        unsigned h0 = f32_to_bf16_rne(v0), h1 = f32_to_bf16_rne(v1);
        float l0 = v0 - __uint_as_float(h0 << 16);
        float l1 = v1 - __uint_as_float(h1 << 16);
        hi[jj] = h0 | (h1 << 16);
        lo[jj] = pack_bf16x2(l0, l1);
    }
    uint4 uh; uh.x = hi[0]; uh.y = hi[1]; uh.z = hi[2]; uh.w = hi[3];
    uint4 ul; ul.x = lo[0]; ul.y = lo[1]; ul.z = lo[2]; ul.w = lo[3];
    whi[slot] = uh;
    wlo[slot] = ul;
}

// ---------------- GEMM via bf16 MFMA (fp32-equivalent via hi/lo split) ----------------
// Y[n,OUTC](bf16, pre-scaled by dinv[row]) = dinv[r] * act(X[n,128]) @ W[128,OUTC]
// act = BN(scale,shift)+ReLU when scale!=nullptr, else identity.
// Per block: 64 rows x OUTC cols. 4 waves; wave w owns col-tiles {w*CTW .. }.
// Operands SWAPPED in mfma (W-frag as A, X-frag as B) so D is row-major per
// lane: lane holds 4 consecutive output cols of one row -> uint2 store.

template <int OUTC>
__global__ __launch_bounds__(256) void gemm_kernel(const float* __restrict__ X,
                                                   const uint4* __restrict__ whi,
                                                   const uint4* __restrict__ wlo,
                                                   const float* __restrict__ scale,
                                                   const float* __restrict__ shift,
                                                   const float* __restrict__ dinv,
                                                   unsigned int* __restrict__ Y, int n) {
    constexpr int NCT = OUTC / 16;
    constexpr int CTW = NCT / 4;   // col-tiles per wave (2 for OUTC=128, 1 for 64)
    __shared__ __align__(16) unsigned short lAhi[64 * 128];  // 16 KB, XOR-swizzled
    __shared__ __align__(16) unsigned short lAlo[64 * 128];  // 16 KB
    __shared__ float ldv[64];
    const int t = threadIdx.x;
    const int base = blockIdx.x * 64;
    const int lane = t & 63;
    const int w = t >> 6;
    const bool bn = (scale != nullptr);

    if (t < 64) { int r = base + t; ldv[t] = (r < n) ? dinv[r] : 0.0f; }

    // B fragments (registers, whole kernel): CTW x 4 kc x {hi,lo}
    bf16x8 bhi[CTW][4], blo[CTW][4];
#pragma unroll
    for (int c = 0; c < CTW; c++) {
        int ct = w * CTW + c;
#pragma unroll
        for (int kc = 0; kc < 4; kc++) {
            int slot = (ct * 4 + kc) * 64 + lane;
            bhi[c][kc] = *reinterpret_cast<const bf16x8*>(whi + slot);
            blo[c][kc] = *reinterpret_cast<const bf16x8*>(wlo + slot);
        }
    }

    // Stage A: coalesced fp32 loads, fused BN+ReLU, hi/lo bf16 split, swizzled LDS.
    const int col4 = (t & 31) * 4;
    float4 sc4, sh4;
    if (bn) {
        sc4 = *(const float4*)&scale[col4];
        sh4 = *(const float4*)&shift[col4];
    }
#pragma unroll
    for (int i = 0; i < 8; i++) {
        int row = i * 8 + (t >> 5);
        int r = base + row;
        float4 xv = make_float4(0.f, 0.f, 0.f, 0.f);
        if (r < n) xv = *(const float4*)&X[(size_t)r * 128 + col4];
        if (bn) {
            xv.x = fmaxf(fmaf(xv.x, sc4.x, sh4.x), 0.0f);
            xv.y = fmaxf(fmaf(xv.y, sc4.y, sh4.y), 0.0f);
            xv.z = fmaxf(fmaf(xv.z, sc4.z, sh4.z), 0.0f);
            xv.w = fmaxf(fmaf(xv.w, sc4.w, sh4.w), 0.0f);
        }
        unsigned h0 = f32_to_bf16_rne(xv.x), h1 = f32_to_bf16_rne(xv.y);
        unsigned h2 = f32_to_bf16_rne(xv.z), h3 = f32_to_bf16_rne(xv.w);
        float l0 = xv.x - __uint_as_float(h0 << 16);
        float l1 = xv.y - __uint_as_float(h1 << 16);
        float l2 = xv.z - __uint_as_float(h2 << 16);
        float l3 = xv.w - __uint_as_float(h3 << 16);
        uint2 ph; ph.x = h0 | (h1 << 16); ph.y = h2 | (h3 << 16);
        uint2 pl; pl.x = pack_bf16x2(l0, l1); pl.y = pack_bf16x2(l2, l3);
        int off = row * 256 + ((col4 * 2) ^ ((row & 7) << 4));
        *(uint2*)((char*)lAhi + off) = ph;
        *(uint2*)((char*)lAlo + off) = pl;
    }
    __syncthreads();

    // Compute: 4 row-tiles of 16; per (rt,kc): 2 LDS frag reads + 3*CTW MFMAs.
    const int arow = lane & 15;
    const int kb16 = (lane >> 4) * 16;
#pragma unroll
    for (int rt = 0; rt < 4; rt++) {
        f32x4 acc[CTW];
#pragma unroll
        for (int c = 0; c < CTW; c++) acc[c] = (f32x4){0.f, 0.f, 0.f, 0.f};
        int row = rt * 16 + arow;
        int rb = row * 256;
        int sw = (row & 7) << 4;
#pragma unroll
        for (int kc = 0; kc < 4; kc++) {
            int off = rb + ((kc * 64 + kb16) ^ sw);
            bf16x8 ah = *(const bf16x8*)((const char*)lAhi + off);
            bf16x8 al = *(const bf16x8*)((const char*)lAlo + off);
#pragma unroll
            for (int c = 0; c < CTW; c++) {
                acc[c] = __builtin_amdgcn_mfma_f32_16x16x32_bf16(bhi[c][kc], ah, acc[c], 0, 0, 0);
                acc[c] = __builtin_amdgcn_mfma_f32_16x16x32_bf16(blo[c][kc], ah, acc[c], 0, 0, 0);
                acc[c] = __builtin_amdgcn_mfma_f32_16x16x32_bf16(bhi[c][kc], al, acc[c], 0, 0, 0);
            }
        }
        int r = base + row;
        if (r < n) {
            float dv = ldv[row];
#pragma unroll
            for (int c = 0; c < CTW; c++) {
                int ct = w * CTW + c;
                uint2 o;
                o.x = pack_bf16x2(acc[c][0] * dv, acc[c][1] * dv);
                o.y = pack_bf16x2(acc[c][2] * dv, acc[c][3] * dv);
                *(uint2*)&Y[(size_t)r * (OUTC / 2) + ct * 8 + (lane >> 4) * 2] = o;
            }
        }
    }
}

// ---------------- aggregation (128 cols): TWO nodes per wave ----------------
// xw rows are pre-scaled by dinv[src]. out[d] = dinv[d]*(sum xw'[s] + xw'[d]) + b.
// 32 lanes per node, uint2 (8B) gathers -> one wave-instruction fetches TWO
// 256B rows; 8-deep batch pipeline => 16 rows in flight per wave (2x MLP vs
// one-node version). All predication per-lane; clamped indices kill the tail.

__global__ __launch_bounds__(256) void agg128_kernel(const unsigned int* __restrict__ xw,
                                                     const int* __restrict__ rowptr,
                                                     const int* __restrict__ cnt,
                                                     const int* __restrict__ esrc,
                                                     const float* __restrict__ dinv,
                                                     const float* __restrict__ bias,
                                                     float* __restrict__ out, int n) {
    const uint2* xw2 = (const uint2*)xw;
    int wid = (blockIdx.x * 256 + threadIdx.x) >> 6;   // wave index
    int lane = threadIdx.x & 63;
    int half = lane >> 5;
    int hl = lane & 31;
    int node = wid * 2 + half;
    bool ok = node < n;
    int nc = ok ? node : 0;

    float di = dinv[nc];
    int beg = rowptr[nc];
    int cv  = ok ? cnt[nc] : 0;
    int last = beg + cv - 1;
    int nb = (cv + 7) >> 3;

    uint2 ap = xw2[(size_t)nc * 32 + hl];
    float ax = bf16_lo(ap.x), ay = bf16_hi(ap.x);
    float az = bf16_lo(ap.y), aw = bf16_hi(ap.y);

    int s[8], sn[8];
    if (nb > 0) {
#pragma unroll
        for (int j = 0; j < 8; j++) {
            int idx = beg + j;
            s[j] = esrc[idx <= last ? idx : last];
        }
    }
    for (int b = 0; b < nb; b++) {
        int ebase = beg + b * 8;
        if (b + 1 < nb) {
#pragma unroll
            for (int j = 0; j < 8; j++) {
                int idx = ebase + 8 + j;
                sn[j] = esrc[idx <= last ? idx : last];
            }
        }
        uint2 v[8];
#pragma unroll
        for (int j = 0; j < 8; j++) v[j] = xw2[(size_t)s[j] * 32 + hl];
        int rem = last - ebase;   // valid j <= rem
#pragma unroll
        for (int j = 0; j < 8; j++) {
            float m = (j <= rem) ? 1.0f : 0.0f;
            ax = fmaf(m, bf16_lo(v[j].x), ax);
            ay = fmaf(m, bf16_hi(v[j].x), ay);
            az = fmaf(m, bf16_lo(v[j].y), az);
            aw = fmaf(m, bf16_hi(v[j].y), aw);
        }
        if (b + 1 < nb) {
#pragma unroll
            for (int j = 0; j < 8; j++) s[j] = sn[j];
        }
    }
    if (ok) {
        float4 bv = ((const float4*)bias)[hl];
        float4 o;
        o.x = fmaf(di, ax, bv.x);
        o.y = fmaf(di, ay, bv.y);
        o.z = fmaf(di, az, bv.z);
        o.w = fmaf(di, aw, bv.w);
        ((float4*)(out + (size_t)node * 128))[hl] = o;
    }
}

// ---------------- aggregation (64-col output layer): TWO nodes per wave ----------------

__global__ __launch_bounds__(256) void agg64_kernel(const unsigned int* __restrict__ xw,
                                                    const int* __restrict__ rowptr,
                                                    const int* __restrict__ cnt,
                                                    const int* __restrict__ esrc,
                                                    const float* __restrict__ dinv,
                                                    const float* __restrict__ bias,
                                                    float* __restrict__ out, int n) {
    int wid = (blockIdx.x * 256 + threadIdx.x) >> 6;
    int lane = threadIdx.x & 63;
    int half = lane >> 5;
    int hl = lane & 31;
    int node = wid * 2 + half;
    bool ok = node < n;
    int nc = ok ? node : 0;

    float di = dinv[nc];
    int beg = rowptr[nc];
    int cv  = ok ? cnt[nc] : 0;
    int last = beg + cv - 1;
    int nb = (cv + 7) >> 3;

    unsigned int ap = xw[(size_t)nc * 32 + hl];
    float ax = bf16_lo(ap), ay = bf16_hi(ap);

    int s[8], sn[8];
    if (nb > 0) {
#pragma unroll
        for (int j = 0; j < 8; j++) {
            int idx = beg + j;
            s[j] = esrc[idx <= last ? idx : last];
        }
    }
    for (int b = 0; b < nb; b++) {
        int ebase = beg + b * 8;
        if (b + 1 < nb) {
#pragma unroll
            for (int j = 0; j < 8; j++) {
                int idx = ebase + 8 + j;
                sn[j] = esrc[idx <= last ? idx : last];
            }
        }
        unsigned int v[8];
#pragma unroll
        for (int j = 0; j < 8; j++) v[j] = xw[(size_t)s[j] * 32 + hl];
        int rem = last - ebase;
#pragma unroll
        for (int j = 0; j < 8; j++) {
            float m = (j <= rem) ? 1.0f : 0.0f;
            ax = fmaf(m, bf16_lo(v[j]), ax);
            ay = fmaf(m, bf16_hi(v[j]), ay);
        }
        if (b + 1 < nb) {
#pragma unroll
            for (int j = 0; j < 8; j++) s[j] = sn[j];
        }
    }
    if (ok) {
        float2 bv = ((const float2*)bias)[hl];
        float2 o;
        o.x = fmaf(di, ax, bv.x);
        o.y = fmaf(di, ay, bv.y);
        ((float2*)(out + (size_t)node * 64))[hl] = o;
    }
}

// ---------------- BatchNorm (training-mode, biased var) ----------------

__global__ void bn_stats_kernel(const float* __restrict__ h, float* __restrict__ sums, int n) {
    int c = threadIdx.x & 127;
    int half = threadIdx.x >> 7;
    float s = 0.0f, q = 0.0f;
    for (int r = blockIdx.x * 2 + half; r < n; r += gridDim.x * 2) {
        float v = h[(size_t)r * 128 + c];
        s += v;
        q = fmaf(v, v, q);
    }
    __shared__ float ls[256], lq[256];
    ls[threadIdx.x] = s; lq[threadIdx.x] = q;
    __syncthreads();
    if (half == 0) {
        s += ls[c + 128];
        q += lq[c + 128];
        atomicAdd(&sums[c], s);
        atomicAdd(&sums[128 + c], q);
    }
}

__global__ void bn_finalize_kernel(const float* __restrict__ sums, const float* __restrict__ g,
                                   const float* __restrict__ be, float* __restrict__ scale,
                                   float* __restrict__ shift, int n) {
    int c = threadIdx.x;  // 128 threads
    float inv_n = 1.0f / (float)n;
    float mean = sums[c] * inv_n;
    float var = sums[128 + c] * inv_n - mean * mean;
    float rstd = rsqrtf(var + BN_EPS);
    float sc = rstd * g[c];
    scale[c] = sc;
    shift[c] = be[c] - mean * sc;
}

// ---------------- launch ----------------

extern "C" void kernel_launch(void* const* d_in, const int* in_sizes, int n_in,
                              void* d_out, int out_size, void* d_ws, size_t ws_size,
                              hipStream_t stream) {
    const float* x   = (const float*)d_in[0];
    const int*   ei  = (const int*)d_in[1];
    const float* W1  = (const float*)d_in[2];
    const float* b1  = (const float*)d_in[3];
    const float* g1  = (const float*)d_in[4];
    const float* be1 = (const float*)d_in[5];
    const float* W2  = (const float*)d_in[6];
    const float* b2  = (const float*)d_in[7];
    const float* g2  = (const float*)d_in[8];
    const float* be2 = (const float*)d_in[9];
    const float* W3  = (const float*)d_in[10];
    const float* b3  = (const float*)d_in[11];

    const int n = in_sizes[0] / 128;
    const int E = in_sizes[1] / 2;
    const int* srcv = ei;
    const int* dstv = ei + E;

    const int G = (E + CHUNK - 1) / CHUNK;      // hist/scatter blocks (196)
    const int HN = BKT * G;                      // H matrix elements (50176)
    const int NB = (n + 511) >> 9;               // used buckets (196)

    char* p = (char*)d_ws;
    auto carve = [&](size_t bytes) -> char* {
        char* q = p;
        p += (bytes + 255) & ~(size_t)255;
        return q;
    };
    int*   cnt    = (int*)carve((size_t)n * 4);
    int*   rowptr = (int*)carve((size_t)n * 4);
    float* dinv   = (float*)carve((size_t)n * 4);
    int*   esrc   = (int*)carve((size_t)E * 4);
    uint2* binned = (uint2*)carve((size_t)E * 8);
    int*   H      = (int*)carve((size_t)HN * 4);
    int*   Hscan  = (int*)carve((size_t)HN * 4);
    float* sums   = (float*)carve(512 * 4);   // [sum1|sq1|sum2|sq2]
    float* bnsc   = (float*)carve(512 * 4);   // [scale1|shift1|scale2|shift2]
    int*   bsum   = (int*)carve(1024 * 4);
    uint4* w1hi   = (uint4*)carve(2048 * 16); // W-frag arrays (hi/lo bf16)
    uint4* w1lo   = (uint4*)carve(2048 * 16);
    uint4* w2hi   = (uint4*)carve(2048 * 16);
    uint4* w2lo   = (uint4*)carve(2048 * 16);
    uint4* w3hi   = (uint4*)carve(1024 * 16);
    uint4* w3lo   = (uint4*)carve(1024 * 16);
    unsigned int* xwb = (unsigned int*)carve((size_t)n * 128 * 2);  // gemm out (bf16 packed, pre-scaled by dinv)
    float* bufB   = (float*)carve((size_t)n * 128 * 4);             // agg out (fp32)

    hipMemsetAsync(sums, 0, 512 * 4, stream);

    int sbH = (HN + 1023) / 1024;    // 49 <= 256

    // W fragment prep (no deps; overlaps CSR build region)
    wprep_kernel<128><<<8, 256, 0, stream>>>(W1, w1hi, w1lo);
    wprep_kernel<128><<<8, 256, 0, stream>>>(W2, w2hi, w2lo);
    wprep_kernel<64><<<4, 256, 0, stream>>>(W3, w3hi, w3lo);

    // bucketed CSR build (single LDS-atomic build kernel; no global N-scan)
    hist_kernel<<<G, 256, 0, stream>>>(dstv, H, E, G);
    blocksum_kernel<<<sbH, 256, 0, stream>>>(H, bsum, HN);
    scan_bsum_kernel<<<1, 256, 0, stream>>>(bsum, sbH);
    scan_write1_kernel<<<sbH, 256, 0, stream>>>(H, bsum, Hscan, HN);
    bin_scatter_kernel<<<G, 256, 0, stream>>>(srcv, dstv, Hscan, binned, E, G);
    bucket_build_kernel<<<NB, 256, 0, stream>>>(binned, Hscan, cnt, rowptr, dinv, esrc, E, G, n);

    int gb = (n + 63) / 64;
    int ab = (n + 7) / 8;   // 2 nodes per wave, 4 waves per block

    // layer 1: gcn(x, W1) + b1
    gemm_kernel<128><<<gb, 256, 0, stream>>>(x, w1hi, w1lo, nullptr, nullptr, dinv, xwb, n);
    agg128_kernel<<<ab, 256, 0, stream>>>(xwb, rowptr, cnt, esrc, dinv, b1, bufB, n);
    bn_stats_kernel<<<512, 256, 0, stream>>>(bufB, sums, n);
    bn_finalize_kernel<<<1, 128, 0, stream>>>(sums, g1, be1, bnsc, bnsc + 128, n);

    // layer 2: gcn(relu(bn1(h)), W2) + b2   (bn1+relu fused into gemm staging)
    gemm_kernel<128><<<gb, 256, 0, stream>>>(bufB, w2hi, w2lo, bnsc, bnsc + 128, dinv, xwb, n);
    agg128_kernel<<<ab, 256, 0, stream>>>(xwb, rowptr, cnt, esrc, dinv, b2, bufB, n);
    bn_stats_kernel<<<512, 256, 0, stream>>>(bufB, sums + 256, n);
    bn_finalize_kernel<<<1, 128, 0, stream>>>(sums + 256, g2, be2, bnsc + 256, bnsc + 384, n);

    // layer 3: gcn(relu(bn2(h)), W3) + b3  -> d_out
    gemm_kernel<64><<<gb, 256, 0, stream>>>(bufB, w3hi, w3lo, bnsc + 256, bnsc + 384, dinv, xwb, n);
    agg64_kernel<<<ab, 256, 0, stream>>>(xwb, rowptr, cnt, esrc, dinv, b3, (float*)d_out, n);
}